// Round 8
// baseline (338.608 us; speedup 1.0000x reference)
//
#include <hip/hip_runtime.h>
#include <hip/hip_bf16.h>

typedef __attribute__((ext_vector_type(8))) __bf16 bf16x8;
typedef __attribute__((ext_vector_type(8))) short short8;
typedef __attribute__((ext_vector_type(4))) float f32x4;

#define LOG2E 1.44269504088896f
#define SCL (0.125f * 1.44269504088896f)   // combine 1/sqrt(64) with log2 domain

static __device__ __forceinline__ ushort f2bf(float f) {
  union { float f; unsigned u; } x; x.f = f;
  unsigned r = x.u + 0x7fffu + ((x.u >> 16) & 1u);
  return (ushort)(r >> 16);
}

static __device__ __forceinline__ unsigned cvt_pk_bf16(float a, float b) {
  unsigned r;
  asm("v_cvt_pk_bf16_f32 %0, %1, %2" : "=v"(r) : "v"(a), "v"(b));
  return r;
}

static __device__ __forceinline__ void gll16(const ushort* g, ushort* l) {
  __builtin_amdgcn_global_load_lds(
      (const __attribute__((address_space(1))) unsigned*)g,
      (__attribute__((address_space(3))) unsigned*)l, 16, 0, 0);
}

// ---------------- fp32 -> bf16 conversion / packing pre-pass ----------------
#define NQ 3145728u
#define NW 589824u
__global__ __launch_bounds__(256)
void cvt_all(const float* __restrict__ q, const float* __restrict__ k,
             const float* __restrict__ v,
             const float* __restrict__ wq, const float* __restrict__ wk,
             const float* __restrict__ wv, const float* __restrict__ wo,
             ushort* __restrict__ dst)
{
  size_t i = ((size_t)blockIdx.x * 256 + threadIdx.x) * 4;
  const float* src; size_t off;
  if (i < NQ)                { src = q;  off = i; }
  else if (i < 2u * NQ)      { src = k;  off = i - NQ; }
  else if (i < 3u * NQ)      { src = v;  off = i - 2u * NQ; }
  else {
    size_t j = i - 3u * NQ;
    if (j < NW)            { src = wq; off = j; }
    else if (j < 2u * NW)  { src = wk; off = j - NW; }
    else if (j < 3u * NW)  { src = wv; off = j - 2u * NW; }
    else                   { src = wo; off = j - 3u * NW; }
  }
  f32x4 x = *(const f32x4*)(src + off);
  uint2 o;
  o.x = cvt_pk_bf16(x[0], x[1]);
  o.y = cvt_pk_bf16(x[2], x[3]);
  *(uint2*)(dst + i) = o;
}

// ---------------- mask bit-pack: int32[2048][2048] -> u64[2048][32] ----------------
__global__ __launch_bounds__(256)
void mask_pack(const int* __restrict__ mask, unsigned long long* __restrict__ mb)
{
  size_t gw = (size_t)blockIdx.x * 4 + (threadIdx.x >> 6);
  int lane = threadIdx.x & 63;
  int mk = mask[gw * 64 + lane];
  unsigned long long bits = __ballot(mk != 0);
  if (lane == 0) mb[gw] = bits;
}

// ---------------- 2-phase double-buffered GEMM: y = A @ W^T + bias ----------------
// MODE 0: out bf16 [B=2,H=12,S=2048,Dk=64]
// MODE 1: out fp32 [4096][768]
// MODE 2: out bf16 V^T layout [bh=24][Dk=64][S=2048]
template<int MODE>
static __device__ __forceinline__ void gemm_core(const ushort* __restrict__ A,
                                                 const ushort* __restrict__ Wrow0,
                                                 const float* __restrict__ bias0,
                                                 void* __restrict__ outv,
                                                 int m0, int c0)
{
  constexpr int K = 768;
  constexpr int BK = 64;
  __shared__ ushort As[2][128 * BK];
  __shared__ ushort Bs[2][128 * BK];
  const int tid  = threadIdx.x;
  const int lane = tid & 63;
  const int wid  = tid >> 6;
  const int wr = (wid >> 1) * 64;
  const int wc = (wid & 1) * 64;

  f32x4 acc[4][4];
#pragma unroll
  for (int i = 0; i < 4; i++)
#pragma unroll
    for (int j = 0; j < 4; j++) acc[i][j] = f32x4{0.f, 0.f, 0.f, 0.f};

  const ushort* gA[4]; const ushort* gB[4];
  int loff[4];
#pragma unroll
  for (int s = 0; s < 4; s++) {
    int idx = tid + s * 256;
    int row = idx >> 3, col = (idx & 7) * 8;
    gA[s] = A     + (size_t)(m0 + row) * K + col;
    gB[s] = Wrow0 + (size_t)row * K + col;
    loff[s] = idx * 8;
  }

  const int fr  = lane & 15;
  const int kg8 = (lane >> 4) * 8;

#pragma unroll
  for (int s = 0; s < 4; s++) {
    gll16(gA[s], &As[0][loff[s]]);
    gll16(gB[s], &Bs[0][loff[s]]);
  }
  __syncthreads();

  int cur = 0;
  for (int t = 0; t < K / BK; t++) {
    if (t < K / BK - 1) {
      const int kt = (t + 1) * BK;
#pragma unroll
      for (int s = 0; s < 4; s++) {
        gll16(gA[s] + kt, &As[cur ^ 1][loff[s]]);
        gll16(gB[s] + kt, &Bs[cur ^ 1][loff[s]]);
      }
    }
    bf16x8 af[2][4], wf[2][4];
#pragma unroll
    for (int kk = 0; kk < 2; kk++) {
#pragma unroll
      for (int i = 0; i < 4; i++) af[kk][i] = *(const bf16x8*)&As[cur][(wr + i * 16 + fr) * BK + kk * 32 + kg8];
#pragma unroll
      for (int j = 0; j < 4; j++) wf[kk][j] = *(const bf16x8*)&Bs[cur][(wc + j * 16 + fr) * BK + kk * 32 + kg8];
    }
#pragma unroll
    for (int kk = 0; kk < 2; kk++)
#pragma unroll
      for (int i = 0; i < 4; i++)
#pragma unroll
        for (int j = 0; j < 4; j++)
          acc[i][j] = __builtin_amdgcn_mfma_f32_16x16x32_bf16(af[kk][i], wf[kk][j], acc[i][j], 0, 0, 0);
    __syncthreads();
    cur ^= 1;
  }

#pragma unroll
  for (int i = 0; i < 4; i++) {
#pragma unroll
    for (int j = 0; j < 4; j++) {
#pragma unroll
      for (int r = 0; r < 4; r++) {
        int m  = m0 + wr + i * 16 + (lane >> 4) * 4 + r;
        int lc = wc + j * 16 + fr;
        float val = acc[i][j][r] + bias0[lc];
        if (MODE == 0) {
          int nn = c0 + lc;
          int hh = nn >> 6, dk = nn & 63;
          ((ushort*)outv)[(((size_t)(m >> 11) * 12 + hh) * 2048 + (m & 2047)) * 64 + dk] = f2bf(val);
        } else if (MODE == 2) {
          int nn = c0 + lc;
          int hh = nn >> 6, dk = nn & 63;
          int bh = (m >> 11) * 12 + hh;
          ((ushort*)outv)[((size_t)bh * 64 + dk) * 2048 + (m & 2047)] = f2bf(val);
        } else {
          ((float*)outv)[(size_t)m * 768 + c0 + lc] = val;
        }
      }
    }
  }
}

__global__ __launch_bounds__(256)
void qkv_gemm2(const ushort* __restrict__ CV,
               const float* __restrict__ bq, const float* __restrict__ bk,
               const float* __restrict__ bv,
               ushort* __restrict__ Qp, ushort* __restrict__ Kp, ushort* __restrict__ Vp)
{
  const int m0 = blockIdx.x * 128;
  const int n0 = blockIdx.y * 128;
  const int proj = n0 / 768;
  const int c0 = n0 - proj * 768;
  const ushort* A  = CV + (size_t)proj * NQ;
  const ushort* Wc = CV + (size_t)3 * NQ;
  const float* bias = (proj == 0) ? bq : (proj == 1) ? bk : bv;
  ushort* O = (proj == 0) ? Qp : (proj == 1) ? Kp : Vp;
  if (proj == 2)
    gemm_core<2>(A, Wc + (size_t)n0 * 768, bias + c0, O, m0, c0);   // V -> transposed layout
  else
    gemm_core<0>(A, Wc + (size_t)n0 * 768, bias + c0, O, m0, c0);
}

__global__ __launch_bounds__(256)
void o_gemm2(const ushort* __restrict__ X, const ushort* __restrict__ Wo,
             const float* __restrict__ bo, float* __restrict__ out)
{
  const int m0 = blockIdx.x * 128;
  const int n0 = blockIdx.y * 128;
  gemm_core<1>(X, Wo + (size_t)n0 * 768, bo + n0, out, m0, n0);
}

// ---------------- Flash attention v3: XOR-swizzled LDS, V^T staging ----------------
__global__ __launch_bounds__(256, 3)
void attn_kernel(const ushort* __restrict__ Qp, const ushort* __restrict__ Kp,
                 const ushort* __restrict__ VpT,
                 const unsigned long long* __restrict__ mb,
                 ushort* __restrict__ X)
{
  constexpr int S = 2048;
  __shared__ ushort Ks[128][64];      // key-major K tile, XOR-swizzled
  __shared__ ushort Vt[64][128];      // d-major V tile, XOR-swizzled
  __shared__ ushort Ps[4][16][128];   // per-wave P tile, XOR-swizzled

  const int tid  = threadIdx.x;
  const int lane = tid & 63;
  const int w    = tid >> 6;
  const int bid  = blockIdx.x;
  const int bh = (bid & 7) + 8 * (bid >> 8);
  const int qb = (bid >> 3) & 31;
  const int b = bh / 12, h = bh % 12;

  const ushort* Qb  = Qp  + (size_t)bh * S * 64;
  const ushort* Kb  = Kp  + (size_t)bh * S * 64;
  const ushort* gVt = VpT + (size_t)bh * 64 * S;   // [64][2048]

  const int q0  = qb * 64;
  const int fr  = lane & 15;
  const int g   = lane >> 4;
  const int kg8 = g * 8;
  const int qrow4 = q0 + w * 16 + g * 4;

  const int qrow = q0 + w * 16 + fr;
  bf16x8 qf0 = *(const bf16x8*)&Qb[(size_t)qrow * 64 + kg8];
  bf16x8 qf1 = *(const bf16x8*)&Qb[(size_t)qrow * 64 + 32 + kg8];

  float m_r[4] = {-1e9f, -1e9f, -1e9f, -1e9f};
  float l_r[4] = {0.f, 0.f, 0.f, 0.f};
  f32x4 accO[4];
#pragma unroll
  for (int ni = 0; ni < 4; ni++) accO[ni] = f32x4{0.f, 0.f, 0.f, 0.f};

  // K staging coords
  const int skey = tid >> 2;
  const int sc0  = (tid & 3) * 16;
  const int kxor = (skey & 7) << 3;
  // V staging coords (direct from V^T global)
  const int vd   = tid >> 4;          // 0..15 base d-row
  const int vkc  = (tid & 15) * 8;    // key-chunk col
  const int vxor = (vd & 7) << 3;

  const uint4* mb4 = (const uint4*)mb;

  short8 kr0, kr1, kr2, kr3, vr0, vr1, vr2, vr3;
  {
    const ushort* kb = Kb + (size_t)skey * 64 + sc0;
    kr0 = *(const short8*)kb;          kr1 = *(const short8*)(kb + 8);
    kr2 = *(const short8*)(kb + 4096); kr3 = *(const short8*)(kb + 4104);
    const ushort* vb = gVt + (size_t)vd * S + vkc;
    vr0 = *(const short8*)vb;
    vr1 = *(const short8*)(vb + 16 * S);
    vr2 = *(const short8*)(vb + 32 * S);
    vr3 = *(const short8*)(vb + 48 * S);
  }

  for (int tt = 0; tt < 16; tt++) {
    __syncthreads();
    *(short8*)&Ks[skey][sc0 ^ kxor]            = kr0;
    *(short8*)&Ks[skey][(sc0 + 8) ^ kxor]      = kr1;
    *(short8*)&Ks[64 + skey][sc0 ^ kxor]       = kr2;
    *(short8*)&Ks[64 + skey][(sc0 + 8) ^ kxor] = kr3;
    *(short8*)&Vt[vd][vkc ^ vxor]       = vr0;
    *(short8*)&Vt[vd + 16][vkc ^ vxor]  = vr1;   // (vd+16)&7 == vd&7
    *(short8*)&Vt[vd + 32][vkc ^ vxor]  = vr2;
    *(short8*)&Vt[vd + 48][vkc ^ vxor]  = vr3;
    __syncthreads();

    uint4 mB[4];
#pragma unroll
    for (int r = 0; r < 4; r++)
      mB[r] = mb4[(size_t)(qrow4 + r) * 16 + tt];

    if (tt < 15) {
      const ushort* kb = Kb + (size_t)((tt + 1) * 128 + skey) * 64 + sc0;
      kr0 = *(const short8*)kb;          kr1 = *(const short8*)(kb + 8);
      kr2 = *(const short8*)(kb + 4096); kr3 = *(const short8*)(kb + 4104);
      const ushort* vb = gVt + (size_t)vd * S + (tt + 1) * 128 + vkc;
      vr0 = *(const short8*)vb;
      vr1 = *(const short8*)(vb + 16 * S);
      vr2 = *(const short8*)(vb + 32 * S);
      vr3 = *(const short8*)(vb + 48 * S);
    }

    // QK^T
    f32x4 sc8[8];
#pragma unroll
    for (int ni = 0; ni < 8; ni++) {
      const int row = ni * 16 + fr;
      const int rx = (row & 7) << 3;
      bf16x8 kf0 = *(const bf16x8*)&Ks[row][kg8 ^ rx];
      bf16x8 kf1 = *(const bf16x8*)&Ks[row][(32 + kg8) ^ rx];
      f32x4 c = {0.f, 0.f, 0.f, 0.f};
      c = __builtin_amdgcn_mfma_f32_16x16x32_bf16(qf0, kf0, c, 0, 0, 0);
      c = __builtin_amdgcn_mfma_f32_16x16x32_bf16(qf1, kf1, c, 0, 0, 0);
      sc8[ni] = c;
    }

    // online softmax (log2 domain)
#pragma unroll
    for (int r = 0; r < 4; r++) {
      float praw[8];
#pragma unroll
      for (int ni = 0; ni < 8; ni++) praw[ni] = sc8[ni][r] * SCL;
      float mx = fmaxf(fmaxf(fmaxf(praw[0], praw[1]), fmaxf(praw[2], praw[3])),
                       fmaxf(fmaxf(praw[4], praw[5]), fmaxf(praw[6], praw[7])));
      mx = fmaxf(mx, __shfl_xor(mx, 1));
      mx = fmaxf(mx, __shfl_xor(mx, 2));
      mx = fmaxf(mx, __shfl_xor(mx, 4));
      mx = fmaxf(mx, __shfl_xor(mx, 8));
      if (mx > m_r[r] + 11.5f) {
        float al = exp2f(m_r[r] - mx);
        m_r[r] = mx;
        l_r[r] *= al;
#pragma unroll
        for (int ni = 0; ni < 4; ni++) accO[ni][r] *= al;
      }
      const float mr = m_r[r];
      unsigned sx = mB[r].x >> fr, sy = mB[r].y >> fr,
               sz = mB[r].z >> fr, sw = mB[r].w >> fr;
      unsigned bits[8] = { sx & 1u, (sx >> 16) & 1u, sy & 1u, (sy >> 16) & 1u,
                           sz & 1u, (sz >> 16) & 1u, sw & 1u, (sw >> 16) & 1u };
      float e[8];
      float ls = 0.f;
#pragma unroll
      for (int ni = 0; ni < 8; ni++) {
        float t = exp2f(praw[ni] - mr);
        t = bits[ni] ? t : 0.f;
        e[ni] = t; ls += t;
      }
      ls += __shfl_xor(ls, 1);
      ls += __shfl_xor(ls, 2);
      ls += __shfl_xor(ls, 4);
      ls += __shfl_xor(ls, 8);
      l_r[r] += ls;
      const int prow = g * 4 + r;
      const int pxor = (prow & 7) << 3;
#pragma unroll
      for (int a = 0; a < 4; a++) {
        unsigned pk = cvt_pk_bf16(e[2 * a], e[2 * a + 1]);
        Ps[w][prow][(a * 32 + fr) ^ pxor]      = (ushort)pk;
        Ps[w][prow][(a * 32 + 16 + fr) ^ pxor] = (ushort)(pk >> 16);
      }
    }

    // PV
    const int fx = (fr & 7) << 3;
#pragma unroll
    for (int ks = 0; ks < 4; ks++) {
      bf16x8 pf = *(const bf16x8*)&Ps[w][fr][(ks * 32 + kg8) ^ fx];
#pragma unroll
      for (int ni = 0; ni < 4; ni++) {
        const int row = ni * 16 + fr;
        bf16x8 vf = *(const bf16x8*)&Vt[row][(ks * 32 + kg8) ^ ((row & 7) << 3)];
        accO[ni] = __builtin_amdgcn_mfma_f32_16x16x32_bf16(pf, vf, accO[ni], 0, 0, 0);
      }
    }
  }

  float inv[4];
#pragma unroll
  for (int r = 0; r < 4; r++) inv[r] = 1.f / l_r[r];
#pragma unroll
  for (int ni = 0; ni < 4; ni++) {
#pragma unroll
    for (int r = 0; r < 4; r++) {
      int qq = qrow4 + r;
      float o = accO[ni][r] * inv[r];
      X[((size_t)b * S + qq) * 768 + h * 64 + ni * 16 + fr] = f2bf(o);
    }
  }
}

extern "C" void kernel_launch(void* const* d_in, const int* in_sizes, int n_in,
                              void* d_out, int out_size, void* d_ws, size_t ws_size,
                              hipStream_t stream) {
  const float* q  = (const float*)d_in[0];
  const float* k  = (const float*)d_in[1];
  const float* v  = (const float*)d_in[2];
  const int* mask = (const int*)d_in[3];
  const float* wq = (const float*)d_in[4];
  const float* bq = (const float*)d_in[5];
  const float* wk = (const float*)d_in[6];
  const float* bk = (const float*)d_in[7];
  const float* wv = (const float*)d_in[8];
  const float* bv = (const float*)d_in[9];
  const float* wo = (const float*)d_in[10];
  const float* bo = (const float*)d_in[11];
  float* out = (float*)d_out;

  ushort* CV = (ushort*)d_ws;
  ushort* Qp = CV + (size_t)3 * NQ + (size_t)4 * NW;
  ushort* Kp = Qp + NQ;
  ushort* Vp = Kp + NQ;      // holds V^T layout [24][64][2048]
  ushort* Xb = Vp + NQ;
  unsigned long long* mbuf = (unsigned long long*)CV;  // aliases q-region (dead after qkv)

  cvt_all<<<11520, 256, 0, stream>>>(q, k, v, wq, wk, wv, wo, CV);
  qkv_gemm2<<<dim3(32, 18), dim3(256), 0, stream>>>(CV, bq, bk, bv, Qp, Kp, Vp);
  mask_pack<<<16384, 256, 0, stream>>>(mask, mbuf);
  attn_kernel<<<768, 256, 0, stream>>>(Qp, Kp, Vp, mbuf, Xb);
  o_gemm2<<<dim3(32, 6), dim3(256), 0, stream>>>(Xb, CV + (size_t)3 * NQ + (size_t)3 * NW, bo, out);
}

// Round 9
// 244.570 us; speedup vs baseline: 1.3845x; 1.3845x over previous
//
#include <hip/hip_runtime.h>
#include <hip/hip_bf16.h>

typedef __attribute__((ext_vector_type(8))) __bf16 bf16x8;
typedef __attribute__((ext_vector_type(8))) short short8;
typedef __attribute__((ext_vector_type(4))) float f32x4;

#define LOG2E 1.44269504088896f
#define SCL (0.125f * 1.44269504088896f)   // 1/sqrt(64) folded into log2 domain

static __device__ __forceinline__ ushort f2bf(float f) {
  union { float f; unsigned u; } x; x.f = f;
  unsigned r = x.u + 0x7fffu + ((x.u >> 16) & 1u);
  return (ushort)(r >> 16);
}

static __device__ __forceinline__ unsigned cvt_pk_bf16(float a, float b) {
  unsigned r;
  asm("v_cvt_pk_bf16_f32 %0, %1, %2" : "=v"(r) : "v"(a), "v"(b));
  return r;
}

static __device__ __forceinline__ void gll16(const ushort* g, ushort* l) {
  __builtin_amdgcn_global_load_lds(
      (const __attribute__((address_space(1))) unsigned*)g,
      (__attribute__((address_space(3))) unsigned*)l, 16, 0, 0);
}

// ---------------- fp32 -> bf16 conversion / packing pre-pass ----------------
#define NQ 3145728u
#define NW 589824u
__global__ __launch_bounds__(256)
void cvt_all(const float* __restrict__ q, const float* __restrict__ k,
             const float* __restrict__ v,
             const float* __restrict__ wq, const float* __restrict__ wk,
             const float* __restrict__ wv, const float* __restrict__ wo,
             ushort* __restrict__ dst)
{
  size_t i = ((size_t)blockIdx.x * 256 + threadIdx.x) * 4;
  const float* src; size_t off;
  if (i < NQ)                { src = q;  off = i; }
  else if (i < 2u * NQ)      { src = k;  off = i - NQ; }
  else if (i < 3u * NQ)      { src = v;  off = i - 2u * NQ; }
  else {
    size_t j = i - 3u * NQ;
    if (j < NW)            { src = wq; off = j; }
    else if (j < 2u * NW)  { src = wk; off = j - NW; }
    else if (j < 3u * NW)  { src = wv; off = j - 2u * NW; }
    else                   { src = wo; off = j - 3u * NW; }
  }
  f32x4 x = *(const f32x4*)(src + off);
  uint2 o;
  o.x = cvt_pk_bf16(x[0], x[1]);
  o.y = cvt_pk_bf16(x[2], x[3]);
  *(uint2*)(dst + i) = o;
}

// ---------------- mask bit-pack: int32[2048][2048] -> u64[2048][32] ----------------
__global__ __launch_bounds__(256)
void mask_pack(const int* __restrict__ mask, unsigned long long* __restrict__ mb)
{
  size_t gw = (size_t)blockIdx.x * 4 + (threadIdx.x >> 6);
  int lane = threadIdx.x & 63;
  int mk = mask[gw * 64 + lane];
  unsigned long long bits = __ballot(mk != 0);
  if (lane == 0) mb[gw] = bits;
}

// ---------------- 2-phase double-buffered GEMM: y = A @ W^T + bias ----------------
// MODE 0: out bf16 [B=2,H=12,S=2048,Dk=64];  MODE 1: out fp32 [4096][768]
template<int MODE>
static __device__ __forceinline__ void gemm_core(const ushort* __restrict__ A,
                                                 const ushort* __restrict__ Wrow0,
                                                 const float* __restrict__ bias0,
                                                 void* __restrict__ outv,
                                                 int m0, int c0)
{
  constexpr int K = 768;
  constexpr int BK = 64;
  __shared__ ushort As[2][128 * BK];
  __shared__ ushort Bs[2][128 * BK];
  const int tid  = threadIdx.x;
  const int lane = tid & 63;
  const int wid  = tid >> 6;
  const int wr = (wid >> 1) * 64;
  const int wc = (wid & 1) * 64;

  f32x4 acc[4][4];
#pragma unroll
  for (int i = 0; i < 4; i++)
#pragma unroll
    for (int j = 0; j < 4; j++) acc[i][j] = f32x4{0.f, 0.f, 0.f, 0.f};

  const ushort* gA[4]; const ushort* gB[4];
  int loff[4];
#pragma unroll
  for (int s = 0; s < 4; s++) {
    int idx = tid + s * 256;
    int row = idx >> 3, col = (idx & 7) * 8;
    gA[s] = A     + (size_t)(m0 + row) * K + col;
    gB[s] = Wrow0 + (size_t)row * K + col;
    loff[s] = idx * 8;
  }

  const int fr  = lane & 15;
  const int kg8 = (lane >> 4) * 8;

#pragma unroll
  for (int s = 0; s < 4; s++) {
    gll16(gA[s], &As[0][loff[s]]);
    gll16(gB[s], &Bs[0][loff[s]]);
  }
  __syncthreads();

  int cur = 0;
  for (int t = 0; t < K / BK; t++) {
    if (t < K / BK - 1) {
      const int kt = (t + 1) * BK;
#pragma unroll
      for (int s = 0; s < 4; s++) {
        gll16(gA[s] + kt, &As[cur ^ 1][loff[s]]);
        gll16(gB[s] + kt, &Bs[cur ^ 1][loff[s]]);
      }
    }
    bf16x8 af[2][4], wf[2][4];
#pragma unroll
    for (int kk = 0; kk < 2; kk++) {
#pragma unroll
      for (int i = 0; i < 4; i++) af[kk][i] = *(const bf16x8*)&As[cur][(wr + i * 16 + fr) * BK + kk * 32 + kg8];
#pragma unroll
      for (int j = 0; j < 4; j++) wf[kk][j] = *(const bf16x8*)&Bs[cur][(wc + j * 16 + fr) * BK + kk * 32 + kg8];
    }
#pragma unroll
    for (int kk = 0; kk < 2; kk++)
#pragma unroll
      for (int i = 0; i < 4; i++)
#pragma unroll
        for (int j = 0; j < 4; j++)
          acc[i][j] = __builtin_amdgcn_mfma_f32_16x16x32_bf16(af[kk][i], wf[kk][j], acc[i][j], 0, 0, 0);
    __syncthreads();
    cur ^= 1;
  }

#pragma unroll
  for (int i = 0; i < 4; i++) {
#pragma unroll
    for (int j = 0; j < 4; j++) {
#pragma unroll
      for (int r = 0; r < 4; r++) {
        int m  = m0 + wr + i * 16 + (lane >> 4) * 4 + r;
        int lc = wc + j * 16 + fr;
        float val = acc[i][j][r] + bias0[lc];
        if (MODE == 0) {
          int nn = c0 + lc;
          int hh = nn >> 6, dk = nn & 63;
          ((ushort*)outv)[(((size_t)(m >> 11) * 12 + hh) * 2048 + (m & 2047)) * 64 + dk] = f2bf(val);
        } else {
          ((float*)outv)[(size_t)m * 768 + c0 + lc] = val;
        }
      }
    }
  }
}

__global__ __launch_bounds__(256)
void qkv_gemm2(const ushort* __restrict__ CV,
               const float* __restrict__ bq, const float* __restrict__ bk,
               const float* __restrict__ bv,
               ushort* __restrict__ Qp, ushort* __restrict__ Kp, ushort* __restrict__ Vp)
{
  const int m0 = blockIdx.x * 128;
  const int n0 = blockIdx.y * 128;
  const int proj = n0 / 768;
  const int c0 = n0 - proj * 768;
  const ushort* A  = CV + (size_t)proj * NQ;
  const ushort* Wc = CV + (size_t)3 * NQ;
  const float* bias = (proj == 0) ? bq : (proj == 1) ? bk : bv;
  ushort* O = (proj == 0) ? Qp : (proj == 1) ? Kp : Vp;
  gemm_core<0>(A, Wc + (size_t)n0 * 768, bias + c0, O, m0, c0);
}

__global__ __launch_bounds__(256)
void o_gemm2(const ushort* __restrict__ X, const ushort* __restrict__ Wo,
             const float* __restrict__ bo, float* __restrict__ out)
{
  const int m0 = blockIdx.x * 128;
  const int n0 = blockIdx.y * 128;
  gemm_core<1>(X, Wo + (size_t)n0 * 768, bo + n0, out, m0, n0);
}

// ---------------- Flash attention v4: swapped QK^T, in-register softmax ----------------
__global__ __launch_bounds__(256, 3)
void attn_kernel(const ushort* __restrict__ Qp, const ushort* __restrict__ Kp,
                 const ushort* __restrict__ Vp,
                 const unsigned long long* __restrict__ mb,
                 ushort* __restrict__ X)
{
  constexpr int S = 2048;
  __shared__ ushort Ks[128][64];      // key-major K tile, XOR-swizzled (R8 proven)
  __shared__ ushort Vt[64][136];      // d-major V tile (R6 proven scalar transpose)
  __shared__ ushort Ps[4][16][128];   // per-wave P tile [q][k], fr-XOR-swizzled

  const int tid  = threadIdx.x;
  const int lane = tid & 63;
  const int w    = tid >> 6;
  const int bid  = blockIdx.x;
  const int bh = (bid & 7) + 8 * (bid >> 8);
  const int qb = (bid >> 3) & 31;
  const int b = bh / 12, h = bh % 12;

  const ushort* Qb = Qp + (size_t)bh * S * 64;
  const ushort* Kb = Kp + (size_t)bh * S * 64;
  const ushort* Vb = Vp + (size_t)bh * S * 64;

  const int q0  = qb * 64;
  const int fr  = lane & 15;
  const int g   = lane >> 4;
  const int g4  = g * 4;
  const int kg8 = g * 8;
  const int qrow4 = q0 + w * 16 + g4;

  // lane's q-row for softmax state is q0+w*16+fr (B-operand of swapped QK^T)
  const int qrow = q0 + w * 16 + fr;
  bf16x8 qf0 = *(const bf16x8*)&Qb[(size_t)qrow * 64 + kg8];
  bf16x8 qf1 = *(const bf16x8*)&Qb[(size_t)qrow * 64 + 32 + kg8];

  float m_s = -1e9f;   // per-lane running max (q = qrow)
  float l_s = 0.f;     // per-lane running sum
  f32x4 accO[4];
#pragma unroll
  for (int ni = 0; ni < 4; ni++) accO[ni] = f32x4{0.f, 0.f, 0.f, 0.f};

  const int skey = tid >> 2;          // 0..63
  const int sc0  = (tid & 3) * 16;
  const int kxor = (skey & 7) << 3;
  const uint4* mb4 = (const uint4*)mb;

  short8 kr0, kr1, kr2, kr3, vr0, vr1, vr2, vr3;
  {
    const ushort* kb = Kb + (size_t)skey * 64 + sc0;
    const ushort* vb = Vb + (size_t)skey * 64 + sc0;
    kr0 = *(const short8*)kb;          kr1 = *(const short8*)(kb + 8);
    kr2 = *(const short8*)(kb + 4096); kr3 = *(const short8*)(kb + 4104);
    vr0 = *(const short8*)vb;          vr1 = *(const short8*)(vb + 8);
    vr2 = *(const short8*)(vb + 4096); vr3 = *(const short8*)(vb + 4104);
  }

  for (int tt = 0; tt < 16; tt++) {
    __syncthreads();
    *(short8*)&Ks[skey][sc0 ^ kxor]            = kr0;
    *(short8*)&Ks[skey][(sc0 + 8) ^ kxor]      = kr1;
    *(short8*)&Ks[64 + skey][sc0 ^ kxor]       = kr2;
    *(short8*)&Ks[64 + skey][(sc0 + 8) ^ kxor] = kr3;
#pragma unroll
    for (int i = 0; i < 8; i++) {
      Vt[sc0 + i][skey]          = (ushort)vr0[i];
      Vt[sc0 + 8 + i][skey]      = (ushort)vr1[i];
      Vt[sc0 + i][64 + skey]     = (ushort)vr2[i];
      Vt[sc0 + 8 + i][64 + skey] = (ushort)vr3[i];
    }
    __syncthreads();

    // mask bits for lane's q-row: ONE uint4 = 128 key-bits
    uint4 mq = mb4[(size_t)qrow * 16 + tt];
    unsigned mw[4] = {mq.x, mq.y, mq.z, mq.w};

    // prefetch next K/V tile into registers
    if (tt < 15) {
      const ushort* kb = Kb + (size_t)((tt + 1) * 128 + skey) * 64 + sc0;
      const ushort* vb = Vb + (size_t)((tt + 1) * 128 + skey) * 64 + sc0;
      kr0 = *(const short8*)kb;          kr1 = *(const short8*)(kb + 8);
      kr2 = *(const short8*)(kb + 4096); kr3 = *(const short8*)(kb + 4104);
      vr0 = *(const short8*)vb;          vr1 = *(const short8*)(vb + 8);
      vr2 = *(const short8*)(vb + 4096); vr3 = *(const short8*)(vb + 4104);
    }

    // swapped QK^T: C[k][q] = mfma(A=K, B=Q) -> lane (fr,g) holds
    // S[k = ni*16 + g4 + r][q = qrow] in sc8[ni][r]
    f32x4 sc8[8];
#pragma unroll
    for (int ni = 0; ni < 8; ni++) {
      const int row = ni * 16 + fr;
      const int rx = (row & 7) << 3;
      bf16x8 kf0 = *(const bf16x8*)&Ks[row][kg8 ^ rx];
      bf16x8 kf1 = *(const bf16x8*)&Ks[row][(32 + kg8) ^ rx];
      f32x4 c = {0.f, 0.f, 0.f, 0.f};
      c = __builtin_amdgcn_mfma_f32_16x16x32_bf16(kf0, qf0, c, 0, 0, 0);
      c = __builtin_amdgcn_mfma_f32_16x16x32_bf16(kf1, qf1, c, 0, 0, 0);
      sc8[ni] = c;
    }

    // all 32 P-values for q=qrow are lane-local
    float p[32];
#pragma unroll
    for (int ni = 0; ni < 8; ni++)
#pragma unroll
      for (int r = 0; r < 4; r++) p[ni * 4 + r] = sc8[ni][r] * SCL;

    // max: in-register tree + 2 shfl (combine the 4 g-copies of each q-row)
    float t16[16];
#pragma unroll
    for (int z = 0; z < 16; z++) t16[z] = fmaxf(p[z], p[z + 16]);
#pragma unroll
    for (int z = 0; z < 8; z++) t16[z] = fmaxf(t16[z], t16[z + 8]);
#pragma unroll
    for (int z = 0; z < 4; z++) t16[z] = fmaxf(t16[z], t16[z + 4]);
    float mx = fmaxf(fmaxf(t16[0], t16[1]), fmaxf(t16[2], t16[3]));
    mx = fmaxf(mx, __shfl_xor(mx, 16));
    mx = fmaxf(mx, __shfl_xor(mx, 32));

    // defer-rescale (T13, log2 units)
    bool need = mx > m_s + 11.5f;
    if (__any(need)) {
      float mn = need ? mx : m_s;
      float al = exp2f(m_s - mn);   // 1.0 when !need
      m_s = mn;
      l_s *= al;
#pragma unroll
      for (int r = 0; r < 4; r++) {
        float alr = __shfl(al, g4 + r);   // alpha of q-row qrow4+r
#pragma unroll
        for (int ni = 0; ni < 4; ni++) accO[ni][r] *= alr;
      }
    }
    const float mr = m_s;

    // exp + mask-zero (bit k of the 128-bit row mask)
#pragma unroll
    for (int ni = 0; ni < 8; ni++) {
      unsigned wv = mw[ni >> 1] >> (((ni & 1) * 16) + g4);
#pragma unroll
      for (int r = 0; r < 4; r++) {
        float t = exp2f(p[ni * 4 + r] - mr);
        p[ni * 4 + r] = ((wv >> r) & 1u) ? t : 0.f;
      }
    }

    // sum: tree + 2 shfl
#pragma unroll
    for (int z = 0; z < 16; z++) t16[z] = p[z] + p[z + 16];
#pragma unroll
    for (int z = 0; z < 8; z++) t16[z] += t16[z + 8];
#pragma unroll
    for (int z = 0; z < 4; z++) t16[z] += t16[z + 4];
    float ls = (t16[0] + t16[1]) + (t16[2] + t16[3]);
    ls += __shfl_xor(ls, 16);
    ls += __shfl_xor(ls, 32);
    l_s += ls;

    // P -> Ps[q=fr][k] (wave-private), packed b64 writes, fr-XOR swizzle
    const int px = (fr & 7) << 3;
#pragma unroll
    for (int ni = 0; ni < 8; ni++) {
      uint2 pk;
      pk.x = cvt_pk_bf16(p[ni * 4 + 0], p[ni * 4 + 1]);
      pk.y = cvt_pk_bf16(p[ni * 4 + 2], p[ni * 4 + 3]);
      *(uint2*)&Ps[w][fr][(ni * 16 + g4) ^ px] = pk;
    }

    // PV: O[q][dk] += P[q][k] V[k][dk]
#pragma unroll
    for (int ks = 0; ks < 4; ks++) {
      bf16x8 pf = *(const bf16x8*)&Ps[w][fr][(ks * 32 + kg8) ^ px];
#pragma unroll
      for (int ni = 0; ni < 4; ni++) {
        bf16x8 vf = *(const bf16x8*)&Vt[ni * 16 + fr][ks * 32 + kg8];
        accO[ni] = __builtin_amdgcn_mfma_f32_16x16x32_bf16(pf, vf, accO[ni], 0, 0, 0);
      }
    }
  }

  // normalize (l for q-row qrow4+r lives in lane fr=g4+r) + store
  float inv[4];
#pragma unroll
  for (int r = 0; r < 4; r++) inv[r] = 1.f / __shfl(l_s, g4 + r);
#pragma unroll
  for (int ni = 0; ni < 4; ni++) {
#pragma unroll
    for (int r = 0; r < 4; r++) {
      int qq = qrow4 + r;
      float o = accO[ni][r] * inv[r];
      X[((size_t)b * S + qq) * 768 + h * 64 + ni * 16 + fr] = f2bf(o);
    }
  }
}

extern "C" void kernel_launch(void* const* d_in, const int* in_sizes, int n_in,
                              void* d_out, int out_size, void* d_ws, size_t ws_size,
                              hipStream_t stream) {
  const float* q  = (const float*)d_in[0];
  const float* k  = (const float*)d_in[1];
  const float* v  = (const float*)d_in[2];
  const int* mask = (const int*)d_in[3];
  const float* wq = (const float*)d_in[4];
  const float* bq = (const float*)d_in[5];
  const float* wk = (const float*)d_in[6];
  const float* bk = (const float*)d_in[7];
  const float* wv = (const float*)d_in[8];
  const float* bv = (const float*)d_in[9];
  const float* wo = (const float*)d_in[10];
  const float* bo = (const float*)d_in[11];
  float* out = (float*)d_out;

  ushort* CV = (ushort*)d_ws;
  ushort* Qp = CV + (size_t)3 * NQ + (size_t)4 * NW;
  ushort* Kp = Qp + NQ;
  ushort* Vp = Kp + NQ;
  ushort* Xb = Vp + NQ;
  unsigned long long* mbuf = (unsigned long long*)CV;  // aliases q-region (dead after qkv)

  cvt_all<<<11520, 256, 0, stream>>>(q, k, v, wq, wk, wv, wo, CV);
  qkv_gemm2<<<dim3(32, 18), dim3(256), 0, stream>>>(CV, bq, bk, bv, Qp, Kp, Vp);
  mask_pack<<<16384, 256, 0, stream>>>(mask, mbuf);
  attn_kernel<<<768, 256, 0, stream>>>(Qp, Kp, Vp, mbuf, Xb);
  o_gemm2<<<dim3(32, 6), dim3(256), 0, stream>>>(Xb, CV + (size_t)3 * NQ + (size_t)3 * NW, bo, out);
}

// Round 10
// 233.848 us; speedup vs baseline: 1.4480x; 1.0458x over previous
//
#include <hip/hip_runtime.h>
#include <hip/hip_bf16.h>

typedef __attribute__((ext_vector_type(8))) __bf16 bf16x8;
typedef __attribute__((ext_vector_type(8))) short short8;
typedef __attribute__((ext_vector_type(4))) float f32x4;

#define LOG2E 1.44269504088896f
#define SCL (0.125f * 1.44269504088896f)   // 1/sqrt(64) folded into log2 domain

static __device__ __forceinline__ ushort f2bf(float f) {
  union { float f; unsigned u; } x; x.f = f;
  unsigned r = x.u + 0x7fffu + ((x.u >> 16) & 1u);
  return (ushort)(r >> 16);
}

static __device__ __forceinline__ unsigned cvt_pk_bf16(float a, float b) {
  unsigned r;
  asm("v_cvt_pk_bf16_f32 %0, %1, %2" : "=v"(r) : "v"(a), "v"(b));
  return r;
}

static __device__ __forceinline__ void gll16(const ushort* g, ushort* l) {
  __builtin_amdgcn_global_load_lds(
      (const __attribute__((address_space(1))) unsigned*)g,
      (__attribute__((address_space(3))) unsigned*)l, 16, 0, 0);
}

// ---------------- fused fp32->bf16 convert + mask bit-pack ----------------
// blocks [0, 11520): convert q,k,v,wq,wk,wv,wo into CV (bf16)
// blocks [11520, 27904): pack mask int32[2048][2048] -> u64[2048][32]
#define NQ 3145728u
#define NW 589824u
#define CVT_BLOCKS 11520
__global__ __launch_bounds__(256)
void cvt_mask(const float* __restrict__ q, const float* __restrict__ k,
              const float* __restrict__ v,
              const float* __restrict__ wq, const float* __restrict__ wk,
              const float* __restrict__ wv, const float* __restrict__ wo,
              ushort* __restrict__ dst,
              const int* __restrict__ mask, unsigned long long* __restrict__ mb)
{
  const int bid = blockIdx.x;
  if (bid >= CVT_BLOCKS) {
    size_t gw = (size_t)(bid - CVT_BLOCKS) * 4 + (threadIdx.x >> 6);
    int lane = threadIdx.x & 63;
    int mk = mask[gw * 64 + lane];
    unsigned long long bits = __ballot(mk != 0);
    if (lane == 0) mb[gw] = bits;
    return;
  }
  size_t i = ((size_t)bid * 256 + threadIdx.x) * 4;
  const float* src; size_t off;
  if (i < NQ)                { src = q;  off = i; }
  else if (i < 2u * NQ)      { src = k;  off = i - NQ; }
  else if (i < 3u * NQ)      { src = v;  off = i - 2u * NQ; }
  else {
    size_t j = i - 3u * NQ;
    if (j < NW)            { src = wq; off = j; }
    else if (j < 2u * NW)  { src = wk; off = j - NW; }
    else if (j < 3u * NW)  { src = wv; off = j - 2u * NW; }
    else                   { src = wo; off = j - 3u * NW; }
  }
  f32x4 x = *(const f32x4*)(src + off);
  uint2 o;
  o.x = cvt_pk_bf16(x[0], x[1]);
  o.y = cvt_pk_bf16(x[2], x[3]);
  *(uint2*)(dst + i) = o;
}

// ---------------- 2-phase double-buffered GEMM: y = A @ W^T + bias ----------------
// MODE 0: out bf16 [B=2,H=12,S=2048,Dk=64];  MODE 1: out fp32 [4096][768]
template<int MODE>
static __device__ __forceinline__ void gemm_core(const ushort* __restrict__ A,
                                                 const ushort* __restrict__ Wrow0,
                                                 const float* __restrict__ bias0,
                                                 void* __restrict__ outv,
                                                 int m0, int c0)
{
  constexpr int K = 768;
  constexpr int BK = 64;
  __shared__ ushort As[2][128 * BK];
  __shared__ ushort Bs[2][128 * BK];
  const int tid  = threadIdx.x;
  const int lane = tid & 63;
  const int wid  = tid >> 6;
  const int wr = (wid >> 1) * 64;
  const int wc = (wid & 1) * 64;

  f32x4 acc[4][4];
#pragma unroll
  for (int i = 0; i < 4; i++)
#pragma unroll
    for (int j = 0; j < 4; j++) acc[i][j] = f32x4{0.f, 0.f, 0.f, 0.f};

  const ushort* gA[4]; const ushort* gB[4];
  int loff[4];
#pragma unroll
  for (int s = 0; s < 4; s++) {
    int idx = tid + s * 256;
    int row = idx >> 3, col = (idx & 7) * 8;
    gA[s] = A     + (size_t)(m0 + row) * K + col;
    gB[s] = Wrow0 + (size_t)row * K + col;
    loff[s] = idx * 8;
  }

  const int fr  = lane & 15;
  const int kg8 = (lane >> 4) * 8;

#pragma unroll
  for (int s = 0; s < 4; s++) {
    gll16(gA[s], &As[0][loff[s]]);
    gll16(gB[s], &Bs[0][loff[s]]);
  }
  __syncthreads();

  int cur = 0;
  for (int t = 0; t < K / BK; t++) {
    if (t < K / BK - 1) {
      const int kt = (t + 1) * BK;
#pragma unroll
      for (int s = 0; s < 4; s++) {
        gll16(gA[s] + kt, &As[cur ^ 1][loff[s]]);
        gll16(gB[s] + kt, &Bs[cur ^ 1][loff[s]]);
      }
    }
    bf16x8 af[2][4], wf[2][4];
#pragma unroll
    for (int kk = 0; kk < 2; kk++) {
#pragma unroll
      for (int i = 0; i < 4; i++) af[kk][i] = *(const bf16x8*)&As[cur][(wr + i * 16 + fr) * BK + kk * 32 + kg8];
#pragma unroll
      for (int j = 0; j < 4; j++) wf[kk][j] = *(const bf16x8*)&Bs[cur][(wc + j * 16 + fr) * BK + kk * 32 + kg8];
    }
#pragma unroll
    for (int kk = 0; kk < 2; kk++)
#pragma unroll
      for (int i = 0; i < 4; i++)
#pragma unroll
        for (int j = 0; j < 4; j++)
          acc[i][j] = __builtin_amdgcn_mfma_f32_16x16x32_bf16(af[kk][i], wf[kk][j], acc[i][j], 0, 0, 0);
    __syncthreads();
    cur ^= 1;
  }

#pragma unroll
  for (int i = 0; i < 4; i++) {
#pragma unroll
    for (int j = 0; j < 4; j++) {
#pragma unroll
      for (int r = 0; r < 4; r++) {
        int m  = m0 + wr + i * 16 + (lane >> 4) * 4 + r;
        int lc = wc + j * 16 + fr;
        float val = acc[i][j][r] + bias0[lc];
        if (MODE == 0) {
          int nn = c0 + lc;
          int hh = nn >> 6, dk = nn & 63;
          ((ushort*)outv)[(((size_t)(m >> 11) * 12 + hh) * 2048 + (m & 2047)) * 64 + dk] = f2bf(val);
        } else {
          ((float*)outv)[(size_t)m * 768 + c0 + lc] = val;
        }
      }
    }
  }
}

__global__ __launch_bounds__(256)
void qkv_gemm2(const ushort* __restrict__ CV,
               const float* __restrict__ bq, const float* __restrict__ bk,
               const float* __restrict__ bv,
               ushort* __restrict__ Qp, ushort* __restrict__ Kp, ushort* __restrict__ Vp)
{
  const int m0 = blockIdx.x * 128;
  const int n0 = blockIdx.y * 128;
  const int proj = n0 / 768;
  const int c0 = n0 - proj * 768;
  const ushort* A  = CV + (size_t)proj * NQ;
  const ushort* Wc = CV + (size_t)3 * NQ;
  const float* bias = (proj == 0) ? bq : (proj == 1) ? bk : bv;
  ushort* O = (proj == 0) ? Qp : (proj == 1) ? Kp : Vp;
  gemm_core<0>(A, Wc + (size_t)n0 * 768, bias + c0, O, m0, c0);
}

__global__ __launch_bounds__(256)
void o_gemm2(const ushort* __restrict__ X, const ushort* __restrict__ Wo,
             const float* __restrict__ bo, float* __restrict__ out)
{
  const int m0 = blockIdx.x * 128;
  const int n0 = blockIdx.y * 128;
  gemm_core<1>(X, Wo + (size_t)n0 * 768, bo + n0, out, m0, n0);
}

// ---------------- Flash attention v5: swapped QK^T + de-conflicted Vt ----------------
__global__ __launch_bounds__(256, 3)
void attn_kernel(const ushort* __restrict__ Qp, const ushort* __restrict__ Kp,
                 const ushort* __restrict__ Vp,
                 const unsigned long long* __restrict__ mb,
                 ushort* __restrict__ X)
{
  constexpr int S = 2048;
  __shared__ ushort Ks[128][64];      // key-major K tile, XOR-swizzled
  __shared__ ushort Vt[64][136];      // d-major V tile; col = (k + 16*(d>>4)) & 127
  __shared__ ushort Ps[4][16][128];   // per-wave P tile [q][k], fr-XOR-swizzled

  const int tid  = threadIdx.x;
  const int lane = tid & 63;
  const int w    = tid >> 6;
  const int bid  = blockIdx.x;
  const int bh = (bid & 7) + 8 * (bid >> 8);
  const int qb = (bid >> 3) & 31;
  const int b = bh / 12, h = bh % 12;

  const ushort* Qb = Qp + (size_t)bh * S * 64;
  const ushort* Kb = Kp + (size_t)bh * S * 64;
  const ushort* Vb = Vp + (size_t)bh * S * 64;

  const int q0  = qb * 64;
  const int fr  = lane & 15;
  const int g   = lane >> 4;
  const int g4  = g * 4;
  const int kg8 = g * 8;
  const int qrow4 = q0 + w * 16 + g4;

  const int qrow = q0 + w * 16 + fr;
  bf16x8 qf0 = *(const bf16x8*)&Qb[(size_t)qrow * 64 + kg8];
  bf16x8 qf1 = *(const bf16x8*)&Qb[(size_t)qrow * 64 + 32 + kg8];

  float m_s = -1e9f;
  float l_s = 0.f;
  f32x4 accO[4];
#pragma unroll
  for (int ni = 0; ni < 4; ni++) accO[ni] = f32x4{0.f, 0.f, 0.f, 0.f};

  const int skey = tid >> 2;          // 0..63
  const int sc0  = (tid & 3) * 16;    // d-block base: 0,16,32,48
  const int kxor = (skey & 7) << 3;
  // Vt write columns: shift by 16*(d>>4) = sc0 (d ranges [sc0, sc0+16) per thread)
  const int vc0 = (skey + sc0) & 127;
  const int vc1 = (64 + skey + sc0) & 127;
  const uint4* mb4 = (const uint4*)mb;

  short8 kr0, kr1, kr2, kr3, vr0, vr1, vr2, vr3;
  {
    const ushort* kb = Kb + (size_t)skey * 64 + sc0;
    const ushort* vb = Vb + (size_t)skey * 64 + sc0;
    kr0 = *(const short8*)kb;          kr1 = *(const short8*)(kb + 8);
    kr2 = *(const short8*)(kb + 4096); kr3 = *(const short8*)(kb + 4104);
    vr0 = *(const short8*)vb;          vr1 = *(const short8*)(vb + 8);
    vr2 = *(const short8*)(vb + 4096); vr3 = *(const short8*)(vb + 4104);
  }

  for (int tt = 0; tt < 16; tt++) {
    __syncthreads();
    *(short8*)&Ks[skey][sc0 ^ kxor]            = kr0;
    *(short8*)&Ks[skey][(sc0 + 8) ^ kxor]      = kr1;
    *(short8*)&Ks[64 + skey][sc0 ^ kxor]       = kr2;
    *(short8*)&Ks[64 + skey][(sc0 + 8) ^ kxor] = kr3;
#pragma unroll
    for (int i = 0; i < 8; i++) {
      Vt[sc0 + i][vc0]     = (ushort)vr0[i];
      Vt[sc0 + 8 + i][vc0] = (ushort)vr1[i];
      Vt[sc0 + i][vc1]     = (ushort)vr2[i];
      Vt[sc0 + 8 + i][vc1] = (ushort)vr3[i];
    }
    __syncthreads();

    uint4 mq = mb4[(size_t)qrow * 16 + tt];
    unsigned mw[4] = {mq.x, mq.y, mq.z, mq.w};

    if (tt < 15) {
      const ushort* kb = Kb + (size_t)((tt + 1) * 128 + skey) * 64 + sc0;
      const ushort* vb = Vb + (size_t)((tt + 1) * 128 + skey) * 64 + sc0;
      kr0 = *(const short8*)kb;          kr1 = *(const short8*)(kb + 8);
      kr2 = *(const short8*)(kb + 4096); kr3 = *(const short8*)(kb + 4104);
      vr0 = *(const short8*)vb;          vr1 = *(const short8*)(vb + 8);
      vr2 = *(const short8*)(vb + 4096); vr3 = *(const short8*)(vb + 4104);
    }

    // swapped QK^T: lane (fr,g) holds S[k=ni*16+g4+r][q=qrow]
    f32x4 sc8[8];
#pragma unroll
    for (int ni = 0; ni < 8; ni++) {
      const int row = ni * 16 + fr;
      const int rx = (row & 7) << 3;
      bf16x8 kf0 = *(const bf16x8*)&Ks[row][kg8 ^ rx];
      bf16x8 kf1 = *(const bf16x8*)&Ks[row][(32 + kg8) ^ rx];
      f32x4 c = {0.f, 0.f, 0.f, 0.f};
      c = __builtin_amdgcn_mfma_f32_16x16x32_bf16(kf0, qf0, c, 0, 0, 0);
      c = __builtin_amdgcn_mfma_f32_16x16x32_bf16(kf1, qf1, c, 0, 0, 0);
      sc8[ni] = c;
    }

    float p[32];
#pragma unroll
    for (int ni = 0; ni < 8; ni++)
#pragma unroll
      for (int r = 0; r < 4; r++) p[ni * 4 + r] = sc8[ni][r] * SCL;

    float t16[16];
#pragma unroll
    for (int z = 0; z < 16; z++) t16[z] = fmaxf(p[z], p[z + 16]);
#pragma unroll
    for (int z = 0; z < 8; z++) t16[z] = fmaxf(t16[z], t16[z + 8]);
#pragma unroll
    for (int z = 0; z < 4; z++) t16[z] = fmaxf(t16[z], t16[z + 4]);
    float mx = fmaxf(fmaxf(t16[0], t16[1]), fmaxf(t16[2], t16[3]));
    mx = fmaxf(mx, __shfl_xor(mx, 16));
    mx = fmaxf(mx, __shfl_xor(mx, 32));

    bool need = mx > m_s + 11.5f;
    if (__any(need)) {
      float mn = need ? mx : m_s;
      float al = exp2f(m_s - mn);
      m_s = mn;
      l_s *= al;
#pragma unroll
      for (int r = 0; r < 4; r++) {
        float alr = __shfl(al, g4 + r);
#pragma unroll
        for (int ni = 0; ni < 4; ni++) accO[ni][r] *= alr;
      }
    }
    const float mr = m_s;

#pragma unroll
    for (int ni = 0; ni < 8; ni++) {
      unsigned wv = mw[ni >> 1] >> (((ni & 1) * 16) + g4);
#pragma unroll
      for (int r = 0; r < 4; r++) {
        float t = exp2f(p[ni * 4 + r] - mr);
        p[ni * 4 + r] = ((wv >> r) & 1u) ? t : 0.f;
      }
    }

#pragma unroll
    for (int z = 0; z < 16; z++) t16[z] = p[z] + p[z + 16];
#pragma unroll
    for (int z = 0; z < 8; z++) t16[z] += t16[z + 8];
#pragma unroll
    for (int z = 0; z < 4; z++) t16[z] += t16[z + 4];
    float ls = (t16[0] + t16[1]) + (t16[2] + t16[3]);
    ls += __shfl_xor(ls, 16);
    ls += __shfl_xor(ls, 32);
    l_s += ls;

    const int px = (fr & 7) << 3;
#pragma unroll
    for (int ni = 0; ni < 8; ni++) {
      uint2 pk;
      pk.x = cvt_pk_bf16(p[ni * 4 + 0], p[ni * 4 + 1]);
      pk.y = cvt_pk_bf16(p[ni * 4 + 2], p[ni * 4 + 3]);
      *(uint2*)&Ps[w][fr][(ni * 16 + g4) ^ px] = pk;
    }

    // PV: vf from shifted-column Vt (col = base + 16*ni mod 128)
#pragma unroll
    for (int ks = 0; ks < 4; ks++) {
      bf16x8 pf = *(const bf16x8*)&Ps[w][fr][(ks * 32 + kg8) ^ px];
#pragma unroll
      for (int ni = 0; ni < 4; ni++) {
        bf16x8 vf = *(const bf16x8*)&Vt[ni * 16 + fr][(ks * 32 + kg8 + ni * 16) & 127];
        accO[ni] = __builtin_amdgcn_mfma_f32_16x16x32_bf16(pf, vf, accO[ni], 0, 0, 0);
      }
    }
  }

  float inv[4];
#pragma unroll
  for (int r = 0; r < 4; r++) inv[r] = 1.f / __shfl(l_s, g4 + r);
#pragma unroll
  for (int ni = 0; ni < 4; ni++) {
#pragma unroll
    for (int r = 0; r < 4; r++) {
      int qq = qrow4 + r;
      float o = accO[ni][r] * inv[r];
      X[((size_t)b * S + qq) * 768 + h * 64 + ni * 16 + fr] = f2bf(o);
    }
  }
}

extern "C" void kernel_launch(void* const* d_in, const int* in_sizes, int n_in,
                              void* d_out, int out_size, void* d_ws, size_t ws_size,
                              hipStream_t stream) {
  const float* q  = (const float*)d_in[0];
  const float* k  = (const float*)d_in[1];
  const float* v  = (const float*)d_in[2];
  const int* mask = (const int*)d_in[3];
  const float* wq = (const float*)d_in[4];
  const float* bq = (const float*)d_in[5];
  const float* wk = (const float*)d_in[6];
  const float* bk = (const float*)d_in[7];
  const float* wv = (const float*)d_in[8];
  const float* bv = (const float*)d_in[9];
  const float* wo = (const float*)d_in[10];
  const float* bo = (const float*)d_in[11];
  float* out = (float*)d_out;

  // ws: CV [3*NQ + 4*NW] | Qp | Kp | Vp | Xb | mb [65536 u64]
  ushort* CV = (ushort*)d_ws;
  ushort* Qp = CV + (size_t)3 * NQ + (size_t)4 * NW;
  ushort* Kp = Qp + NQ;
  ushort* Vp = Kp + NQ;
  ushort* Xb = Vp + NQ;
  unsigned long long* mbuf = (unsigned long long*)(Xb + NQ);  // own region (written same kernel as CV)

  cvt_mask<<<27904, 256, 0, stream>>>(q, k, v, wq, wk, wv, wo, CV, mask, mbuf);
  qkv_gemm2<<<dim3(32, 18), dim3(256), 0, stream>>>(CV, bq, bk, bv, Qp, Kp, Vp);
  attn_kernel<<<768, 256, 0, stream>>>(Qp, Kp, Vp, mbuf, Xb);
  o_gemm2<<<dim3(32, 6), dim3(256), 0, stream>>>(Xb, CV + (size_t)3 * NQ + (size_t)3 * NW, bo, out);
}